// Round 6
// baseline (258.583 us; speedup 1.0000x reference)
//
#include <hip/hip_runtime.h>
#include <hip/hip_fp16.h>
#include <cfloat>
#include <cmath>
#include <cstdint>

#define NN 8192
#define DD 16
#define EPSF 1e-8f
#define CH 8            // j-chunks in lean pass
#define CHJ 1024        // j per chunk
#define CAP 320         // candidate buffer per row

typedef float4 f4;
typedef _Float16 f16x4 __attribute__((ext_vector_type(4)));
typedef _Float16 f16x2 __attribute__((ext_vector_type(2)));
typedef float f32x4 __attribute__((ext_vector_type(4)));

__device__ __forceinline__ unsigned umn(unsigned a, unsigned b) { return a < b ? a : b; }
__device__ __forceinline__ unsigned umx(unsigned a, unsigned b) { return a < b ? b : a; }

__device__ __forceinline__ uint32_t pkrtz(float a, float b) {
    return __builtin_bit_cast(uint32_t, __builtin_amdgcn_cvt_pkrtz(a, b));
}

// raw v_sqrt_f32 (~1 ulp) instead of libm sqrtf's multi-inst fixup sequence
__device__ __forceinline__ float fsqrt(float x) {
#if defined(__has_builtin) && __has_builtin(__builtin_amdgcn_sqrtf)
    return __builtin_amdgcn_sqrtf(x);
#else
    return sqrtf(x);
#endif
}

// exact wave-shared top-15 insert (SGPR-side), for the rare fallback path
__device__ __forceinline__ void topk_insert(unsigned (&lst)[15], unsigned& T, unsigned u) {
    unsigned long long m = __ballot(u < T);
    while (m) {
        int ln = (int)(__ffsll(m) - 1);
        unsigned v = (unsigned)__builtin_amdgcn_readlane((int)u, ln);
#pragma unroll
        for (int c = 0; c < 15; c++) {
            unsigned lo = umn(lst[c], v);
            unsigned hi = umx(lst[c], v);
            lst[c] = lo;
            v = hi;
        }
        T = lst[14];
        m &= m - 1;
        m &= __ballot(u < T);
    }
}

// ---------------- column-stat partials ----------------
__device__ __forceinline__ void colstat_reduce_store(const float h[DD], double* __restrict__ part,
                                                     int blk, int tid) {
    const int lane = tid & 63, wid = tid >> 6;
    double s[DD], s2[DD];
#pragma unroll
    for (int c = 0; c < DD; c++) { double a = (double)h[c]; s[c] = a; s2[c] = a * a; }
#pragma unroll
    for (int c = 0; c < DD; c++) {
#pragma unroll
        for (int off = 1; off < 64; off <<= 1) {
            s[c] += __shfl_xor(s[c], off);
            s2[c] += __shfl_xor(s2[c], off);
        }
    }
    __shared__ double red[4][2 * DD];
    if (lane == 0) {
#pragma unroll
        for (int c = 0; c < DD; c++) { red[wid][c] = s[c]; red[wid][DD + c] = s2[c]; }
    }
    __syncthreads();
    if (tid < 2 * DD) {
        double t = red[0][tid] + red[1][tid] + red[2][tid] + red[3][tid];
        part[(size_t)blk * 2 * DD + tid] = t;
    }
}

__global__ __launch_bounds__(256) void k_stats_part_x(const float* __restrict__ x,
                                                      double* __restrict__ part) {
    const int i = blockIdx.x * 256 + threadIdx.x;
    float h[DD];
    const f4* xr = (const f4*)(x + (size_t)i * DD);
#pragma unroll
    for (int q = 0; q < 4; q++) {
        f4 v = xr[q];
        h[4*q+0] = v.x; h[4*q+1] = v.y; h[4*q+2] = v.z; h[4*q+3] = v.w;
    }
    colstat_reduce_store(h, part, blockIdx.x, threadIdx.x);
}

__global__ __launch_bounds__(64) void k_stats_fin1(const double* __restrict__ part,
                                                   float* __restrict__ mean,
                                                   float* __restrict__ stdx) {
    const int c = threadIdx.x;
    if (c < DD) {
        double s = 0.0, q = 0.0;
        for (int b = 0; b < 32; b++) {
            s += part[(size_t)b * 2 * DD + c];
            q += part[(size_t)b * 2 * DD + DD + c];
        }
        double mu = s / (double)NN;
        double var = (q - s * s / (double)NN) / (double)(NN - 1);
        mean[c] = (float)mu;
        stdx[c] = (float)sqrt(var > 0.0 ? var : 0.0);
    }
}

// ---------------- center: xc=x-mean (f32), packed fp16 rows, sq of ROUNDED pts, zero cnt ----------------
__global__ __launch_bounds__(256) void k_center(const float* __restrict__ x,
                                                const float* __restrict__ meanp,
                                                float* __restrict__ xc,
                                                uint32_t* __restrict__ xch,
                                                float* __restrict__ sqh,
                                                unsigned* __restrict__ cnt) {
    const int i = blockIdx.x * 256 + threadIdx.x;
    const f4* mr = (const f4*)meanp;
    const f4* xr = (const f4*)(x + (size_t)i * DD);
    f4* xo = (f4*)(xc + (size_t)i * DD);
    uint32_t* xh = xch + (size_t)i * 8;
    float s = 0.f;
#pragma unroll
    for (int q = 0; q < 4; q++) {
        f4 m = mr[q];
        f4 v = xr[q];
        v.x -= m.x; v.y -= m.y; v.z -= m.z; v.w -= m.w;
        xo[q] = v;
        _Float16 h0 = (_Float16)v.x, h1 = (_Float16)v.y, h2 = (_Float16)v.z, h3 = (_Float16)v.w;
        float r0 = (float)h0, r1 = (float)h1, r2 = (float)h2, r3 = (float)h3;
        s += r0 * r0 + r1 * r1 + r2 * r2 + r3 * r3;
        f16x2 p0 = {h0, h1}, p1 = {h2, h3};
        xh[q * 2 + 0] = __builtin_bit_cast(uint32_t, p0);
        xh[q * 2 + 1] = __builtin_bit_cast(uint32_t, p1);
    }
    sqh[i] = s;
    cnt[i] = 0;
}

// ---------------- thresh: per row, exact 15th-smallest d2 over a 512-col half ----------------
// block = (iG 0..63)*2 + hc; 8 waves x 16 rows; j in [hc*512, hc*512+512)
__global__ __launch_bounds__(512, 2) void k_thresh(const uint32_t* __restrict__ xch,
                                                   const float* __restrict__ sqh,
                                                   float* __restrict__ thr) {
    __shared__ uint32_t tileA[8 * 512];   // frag-order, 16KB
    __shared__ float sqs[512];            // 2KB
    __shared__ float lists[8][64][15];    // 30KB
    const int tid = threadIdx.x, wid = tid >> 6, lane = tid & 63;
    const int r = lane & 15, h = lane >> 4;
    const int iG = blockIdx.x >> 1, hc = blockIdx.x & 1;
    const int jbase = hc << 9;
    const int i0 = (iG * 8 + wid) << 4;
    const int i = i0 + r;

    uint2 bu = *(const uint2*)(xch + (size_t)i * 8 + h * 2);
    f16x4 bf = __builtin_bit_cast(f16x4, bu);
    const float sqi = sqh[i];

    {
        int jl = tid;
        const uint4* src = (const uint4*)(xch + (size_t)(jbase + jl) * 8);
        uint4 a = src[0], b = src[1];
        uint32_t* base = tileA + ((jl >> 4) * 128 + (jl & 15) * 2);
        *(uint2*)(base)      = make_uint2(a.x, a.y);
        *(uint2*)(base + 32) = make_uint2(a.z, a.w);
        *(uint2*)(base + 64) = make_uint2(b.x, b.y);
        *(uint2*)(base + 96) = make_uint2(b.z, b.w);
        sqs[jl] = sqh[jbase + jl];
    }
    __syncthreads();

    unsigned lst[15];
#pragma unroll
    for (int c = 0; c < 15; c++) lst[c] = 0x7F7FFFFFu;
    unsigned T = 0x7F7FFFFFu, Tg = 0x7F7FFFFFu;

    for (int jt = 0; jt < 32; jt++) {
        uint2 au = *(const uint2*)(tileA + (jt * 128 + lane * 2));
        f16x4 af = __builtin_bit_cast(f16x4, au);
        f32x4 dot = __builtin_amdgcn_mfma_f32_16x16x16f16(af, bf, (f32x4){0.f, 0.f, 0.f, 0.f}, 0, 0, 0);
        f32x4 sq4 = *(const f32x4*)&sqs[jt * 16 + h * 4];
        bool fired = false;
#pragma unroll
        for (int q = 0; q < 4; q++) {
            float d2 = fmaf(-2.0f, dot[q], sqi + sq4[q]);
            float d2c = fmaxf(d2, 0.0f);
            unsigned u = __float_as_uint(d2c);
            if (u < Tg) {
                fired = true;
#pragma unroll
                for (int c = 0; c < 15; c++) {
                    unsigned lo = umn(lst[c], u), hi = umx(lst[c], u);
                    lst[c] = lo; u = hi;
                }
                T = lst[14];
            }
        }
        if (__any(fired)) {
            unsigned t1 = umn(T, (unsigned)__shfl_xor((int)T, 16));
            Tg = umn(t1, (unsigned)__shfl_xor((int)t1, 32));
        }
    }
    // merge 4 per-lane sorted lists -> row 15th over this half
#pragma unroll
    for (int c = 0; c < 15; c++) lists[wid][lane][c] = __uint_as_float(lst[c]);
    __syncthreads();
    if (h == 0) {
        int p0 = 0, p1 = 0, p2 = 0, p3 = 0;
        float m = 0.f;
        for (int rr = 0; rr < 15; rr++) {
            float v0 = (p0 < 15) ? lists[wid][r +  0][p0] : FLT_MAX;
            float v1 = (p1 < 15) ? lists[wid][r + 16][p1] : FLT_MAX;
            float v2 = (p2 < 15) ? lists[wid][r + 32][p2] : FLT_MAX;
            float v3 = (p3 < 15) ? lists[wid][r + 48][p3] : FLT_MAX;
            m = fminf(fminf(v0, v1), fminf(v2, v3));
            if (v0 == m) p0++; else if (v1 == m) p1++; else if (v2 == m) p2++; else p3++;
        }
        thr[(size_t)i * 2 + hc] = m;  // 15th smallest of this half
    }
}

// ---------------- pass1 lean: s1/s2 partials + candidate dump (d2 <= T_i) ----------------
__global__ __launch_bounds__(512, 2) void k_pass1_lean(const uint32_t* __restrict__ xch,
                                                       const float* __restrict__ sqh,
                                                       const float* __restrict__ thr,
                                                       float* __restrict__ s1p,
                                                       float* __restrict__ s2p,
                                                       unsigned* __restrict__ cnt,
                                                       float* __restrict__ cand) {
    __shared__ uint32_t tileA[8 * CHJ];   // 32KB frag-order
    __shared__ float sqs[CHJ];            // 4KB
    const int tid = threadIdx.x, wid = tid >> 6, lane = tid & 63;
    const int r = lane & 15, h = lane >> 4;
    const int iG = blockIdx.x >> 3, chunk = blockIdx.x & 7;
    const int jbase = chunk << 10;
    const int i0 = (iG * 8 + wid) << 4;
    const int i = i0 + r;

    uint2 bu = *(const uint2*)(xch + (size_t)i * 8 + h * 2);
    f16x4 bf = __builtin_bit_cast(f16x4, bu);
    const float sqi = sqh[i];
    const float Tf = fminf(thr[(size_t)i * 2], thr[(size_t)i * 2 + 1]);  // >= true row 15th

#pragma unroll
    for (int s = 0; s < 2; s++) {
        int jl = tid + s * 512;
        const uint4* src = (const uint4*)(xch + (size_t)(jbase + jl) * 8);
        uint4 a = src[0], b = src[1];
        uint32_t* base = tileA + ((jl >> 4) * 128 + (jl & 15) * 2);
        *(uint2*)(base)      = make_uint2(a.x, a.y);
        *(uint2*)(base + 32) = make_uint2(a.z, a.w);
        *(uint2*)(base + 64) = make_uint2(b.x, b.y);
        *(uint2*)(base + 96) = make_uint2(b.z, b.w);
        sqs[jl] = sqh[jbase + jl];
    }
    __syncthreads();

    float s1 = 0.f, s2 = 0.f;
    for (int jt = 0; jt < CHJ / 16; jt++) {
        uint2 au = *(const uint2*)(tileA + (jt * 128 + lane * 2));
        f16x4 af = __builtin_bit_cast(f16x4, au);
        f32x4 dot = __builtin_amdgcn_mfma_f32_16x16x16f16(af, bf, (f32x4){0.f, 0.f, 0.f, 0.f}, 0, 0, 0);
        f32x4 sq4 = *(const f32x4*)&sqs[jt * 16 + h * 4];
#pragma unroll
        for (int q = 0; q < 4; q++) {
            float d2 = fmaf(-2.0f, dot[q], sqi + sq4[q]);
            float d2c = fmaxf(d2, 0.0f);
            s1 += fsqrt(d2c);
            s2 += d2c;
            if (d2c <= Tf) {  // rare (~2.3%/lane-value); ties-inclusive
                unsigned idx = atomicAdd(&cnt[i], 1u);
                if (idx < CAP) cand[(size_t)i * CAP + idx] = d2c;
            }
        }
    }
    s1 += __shfl_xor(s1, 16); s1 += __shfl_xor(s1, 32);
    s2 += __shfl_xor(s2, 16); s2 += __shfl_xor(s2, 32);
    if (h == 0) {
        s1p[(size_t)i * CH + chunk] = s1;
        s2p[(size_t)i * CH + chunk] = s2;
    }
}

// ---------------- sel15: exact top-15 per row from candidates (fallback: full rescan) ----------------
__global__ __launch_bounds__(512) void k_sel15(const unsigned* __restrict__ cnt,
                                               const float* __restrict__ cand,
                                               const uint32_t* __restrict__ xch,
                                               const float* __restrict__ sqh,
                                               float* __restrict__ sml) {
    const int tid = threadIdx.x, wid = tid >> 6, lane = tid & 63;
    const int i = blockIdx.x * 8 + wid;
    const unsigned n = cnt[i];
    if (n <= CAP) {
        const float* src = cand + (size_t)i * CAP;
        float v0 = (lane +   0 < (int)n) ? src[lane +   0] : FLT_MAX;
        float v1 = (lane +  64 < (int)n) ? src[lane +  64] : FLT_MAX;
        float v2 = (lane + 128 < (int)n) ? src[lane + 128] : FLT_MAX;
        float v3 = (lane + 192 < (int)n) ? src[lane + 192] : FLT_MAX;
        float v4 = (lane + 256 < (int)n) ? src[lane + 256] : FLT_MAX;
        for (int rr = 0; rr < 15; rr++) {
            float m = fminf(fminf(fminf(v0, v1), fminf(v2, v3)), v4);
            float wm = m;
#pragma unroll
            for (int off = 1; off < 64; off <<= 1) wm = fminf(wm, __shfl_xor(wm, off));
            unsigned long long b = __ballot(m == wm);
            if (lane == (int)(__ffsll(b) - 1)) {  // consume exactly one slot
                if (v0 == wm) v0 = FLT_MAX;
                else if (v1 == wm) v1 = FLT_MAX;
                else if (v2 == wm) v2 = FLT_MAX;
                else if (v3 == wm) v3 = FLT_MAX;
                else v4 = FLT_MAX;
            }
            if (lane == 0) sml[(size_t)i * 15 + rr] = wm;
        }
    } else {
        // overflow fallback (expected never): exact full-row rescan, wave-shared list
        uint32_t xi[8];
        {
            const uint4* p = (const uint4*)(xch + (size_t)i * 8);
            uint4 a = p[0], b = p[1];
            xi[0] = a.x; xi[1] = a.y; xi[2] = a.z; xi[3] = a.w;
            xi[4] = b.x; xi[5] = b.y; xi[6] = b.z; xi[7] = b.w;
        }
        const float sqi = sqh[i];
        unsigned lst[15];
#pragma unroll
        for (int c = 0; c < 15; c++) lst[c] = 0x7F7FFFFFu;
        unsigned T = 0x7F7FFFFFu;
        for (int jb = 0; jb < NN; jb += 64) {
            int j = jb + lane;
            const uint4* p = (const uint4*)(xch + (size_t)j * 8);
            uint4 a = p[0], b = p[1];
            uint32_t xj[8] = {a.x, a.y, a.z, a.w, b.x, b.y, b.z, b.w};
            float dot = 0.f;
#pragma unroll
            for (int c = 0; c < 8; c++)
                dot = __builtin_amdgcn_fdot2(__builtin_bit_cast(f16x2, xi[c]),
                                             __builtin_bit_cast(f16x2, xj[c]), dot, false);
            float d2c = fmaxf(fmaf(-2.0f, dot, sqi + sqh[j]), 0.0f);
            topk_insert(lst, T, __float_as_uint(d2c));
        }
        if (lane == 0) {
#pragma unroll
            for (int c = 0; c < 15; c++) sml[(size_t)i * 15 + c] = __uint_as_float(lst[c]);
        }
    }
}

// ---------------- density from s1/s2 partials ----------------
__global__ __launch_bounds__(256) void k_merge_den(const float* __restrict__ s1p,
                                                   const float* __restrict__ s2p,
                                                   float* __restrict__ den) {
    const int i = blockIdx.x * 256 + threadIdx.x;
    double g1 = 0.0, g2 = 0.0;
#pragma unroll
    for (int c = 0; c < CH; c++) {
        g1 += (double)s1p[(size_t)i * CH + c];
        g2 += (double)s2p[(size_t)i * CH + c];
    }
    double var = (g2 - g1 * g1 / (double)NN) / (double)(NN - 1);
    den[i] = (float)sqrt(var > 0.0 ? var : 0.0);
}

// ---------------- global adaptive k ----------------
__global__ __launch_bounds__(1024) void k_adaptk(const float* __restrict__ density,
                                                 int* __restrict__ kout) {
    const int tid = threadIdx.x;
    __shared__ float redf[16];
    __shared__ int redi[16];
    __shared__ float dmax_sh;
    const int wid = tid >> 6, lane = tid & 63;
    float mx = 0.f;
    for (int r = tid; r < NN; r += 1024) mx = fmaxf(mx, density[r]);
#pragma unroll
    for (int off = 1; off < 64; off <<= 1) mx = fmaxf(mx, __shfl_xor(mx, off));
    if (lane == 0) redf[wid] = mx;
    __syncthreads();
    if (tid == 0) {
        float m = redf[0];
        for (int w = 1; w < 16; w++) m = fmaxf(m, redf[w]);
        dmax_sh = m;
    }
    __syncthreads();
    const float dmax = dmax_sh + EPSF;
    int ks = 0;
    for (int r = tid; r < NN; r += 1024) {
        float f = density[r] / dmax;
        float kf = fminf(fmaxf(5.0f + 10.0f * f, 5.0f), 20.0f);
        ks += (int)kf;
    }
#pragma unroll
    for (int off = 1; off < 64; off <<= 1) ks += __shfl_xor(ks, off);
    if (lane == 0) redi[wid] = ks;
    __syncthreads();
    if (tid == 0) {
        int t = 0;
        for (int w = 0; w < 16; w++) t += redi[w];
        float meank = (float)t / (float)NN;
        kout[0] = (int)meank;
    }
}

// ---------------- drift (MFMA QK + MFMA PV): partial numerator/wsum per chunk ----------------
__global__ __launch_bounds__(512, 2) void k_drift_mfma(const uint32_t* __restrict__ xch,
                                                       const float* __restrict__ sqh,
                                                       const float* __restrict__ sml,
                                                       const int* __restrict__ kptr,
                                                       float* __restrict__ nump,
                                                       float* __restrict__ wsp) {
    __shared__ uint32_t tileA[8 * 512];    // frag-order, 16KB
    __shared__ uint32_t tileT[16 * 256];   // transposed [d][jpair] with +2d rotation, 16KB
    __shared__ float sqs[512];             // 2KB
    const int tid = threadIdx.x, wid = tid >> 6, lane = tid & 63;
    const int r = lane & 15, h = lane >> 4;
    const int iG = blockIdx.x >> 3, chunk = blockIdx.x & 7;
    const int i0 = (iG * 8 + wid) << 4;
    const int i = i0 + r;

    const int k = kptr[0];
    const float sig2 = sml[(size_t)i * 15 + (k - 1)];  // k-th smallest d2 == sigma^2
    const float ninv = -1.0f / (2.0f * sig2 + EPSF);
    uint2 bu = *(const uint2*)(xch + (size_t)i * 8 + h * 2);
    f16x4 bf = __builtin_bit_cast(f16x4, bu);
    const float sqi = sqh[i];

    f32x4 acc = {0.f, 0.f, 0.f, 0.f};
    float ws = 0.f;

#pragma unroll 1
    for (int half = 0; half < 2; half++) {
        const int jb = (chunk << 10) + (half << 9);
        {
            int jl = tid;
            const uint4* src = (const uint4*)(xch + (size_t)(jb + jl) * 8);
            uint4 a = src[0], b = src[1];
            uint32_t* base = tileA + ((jl >> 4) * 128 + (jl & 15) * 2);
            *(uint2*)(base)      = make_uint2(a.x, a.y);
            *(uint2*)(base + 32) = make_uint2(a.z, a.w);
            *(uint2*)(base + 64) = make_uint2(b.x, b.y);
            *(uint2*)(base + 96) = make_uint2(b.z, b.w);
            sqs[jl] = sqh[jb + jl];
            if (tid < 256) {
                int jp = tid;
                const uint4* sA = (const uint4*)(xch + (size_t)(jb + 2 * jp) * 8);
                const uint4* sB = (const uint4*)(xch + (size_t)(jb + 2 * jp + 1) * 8);
                uint4 a0 = sA[0], a1 = sA[1], b0 = sB[0], b1 = sB[1];
                uint32_t rA[8] = {a0.x, a0.y, a0.z, a0.w, a1.x, a1.y, a1.z, a1.w};
                uint32_t rB[8] = {b0.x, b0.y, b0.z, b0.w, b1.x, b1.y, b1.z, b1.w};
#pragma unroll
                for (int d = 0; d < 16; d++) {
                    uint32_t lo = (d & 1) ? (rA[d >> 1] >> 16) : (rA[d >> 1] & 0xFFFFu);
                    uint32_t hi = (d & 1) ? (rB[d >> 1] & 0xFFFF0000u) : (rB[d >> 1] << 16);
                    tileT[d * 256 + ((jp + 2 * d) & 255)] = lo | hi;
                }
            }
        }
        __syncthreads();
        for (int jt = 0; jt < 32; jt++) {
            uint2 au = *(const uint2*)(tileA + (jt * 128 + lane * 2));
            f16x4 af = __builtin_bit_cast(f16x4, au);
            f32x4 dot = __builtin_amdgcn_mfma_f32_16x16x16f16(af, bf, (f32x4){0.f, 0.f, 0.f, 0.f}, 0, 0, 0);
            f32x4 sq4 = *(const f32x4*)&sqs[jt * 16 + h * 4];
            float w0, w1, w2, w3;
            {
                float d2, d;
                d2 = fmaf(-2.f, dot[0], sqi + sq4[0]); d = fsqrt(fmaxf(d2, 0.f)); w0 = __expf(d * ninv);
                d2 = fmaf(-2.f, dot[1], sqi + sq4[1]); d = fsqrt(fmaxf(d2, 0.f)); w1 = __expf(d * ninv);
                d2 = fmaf(-2.f, dot[2], sqi + sq4[2]); d = fsqrt(fmaxf(d2, 0.f)); w2 = __expf(d * ninv);
                d2 = fmaf(-2.f, dot[3], sqi + sq4[3]); d = fsqrt(fmaxf(d2, 0.f)); w3 = __expf(d * ninv);
            }
            ws += (w0 + w1) + (w2 + w3);
            uint2 wp = make_uint2(pkrtz(w0, w1), pkrtz(w2, w3));
            f16x4 wf = __builtin_bit_cast(f16x4, wp);
            int jp0 = jt * 8 + h * 2;
            uint2 tv = *(const uint2*)(tileT + (r * 256 + ((jp0 + 2 * r) & 255)));
            f16x4 btf = __builtin_bit_cast(f16x4, tv);
            acc = __builtin_amdgcn_mfma_f32_16x16x16f16(wf, btf, acc, 0, 0, 0);
        }
        __syncthreads();
    }
    ws += __shfl_xor(ws, 16); ws += __shfl_xor(ws, 32);
    if (h == 0) wsp[(size_t)i * CH + chunk] = ws;
#pragma unroll
    for (int q = 0; q < 4; q++) {
        int irow = i0 + h * 4 + q;
        nump[((size_t)irow * CH + chunk) * 16 + r] = acc[q];
    }
}

// ---------------- merge drift partials ----------------
__global__ __launch_bounds__(256) void k_merge_drift(const float* __restrict__ nump,
                                                     const float* __restrict__ wsp,
                                                     float* __restrict__ drf) {
    const int t = blockIdx.x * 256 + threadIdx.x;
    const int i = t >> 4, d = t & 15;
    float s = 0.f;
#pragma unroll
    for (int c = 0; c < CH; c++) s += nump[((size_t)i * CH + c) * 16 + d];
    float w = 0.f;
#pragma unroll
    for (int c = 0; c < CH; c++) w += wsp[(size_t)i * CH + c];
    drf[t] = s / (w + EPSF);
}

// ---------------- fused: h = xc + step*(drift-xc) + 0.01*noise; col-stat partials ----------------
__global__ __launch_bounds__(256) void k_hpre_stats(const float* __restrict__ xc,
                                                    const float* __restrict__ drift,
                                                    const float* __restrict__ noise,
                                                    const float* __restrict__ alpha,
                                                    float* __restrict__ hpre,
                                                    double* __restrict__ part) {
    const int i = blockIdx.x * 256 + threadIdx.x;
    const float step = powf(16.0f, -alpha[0]);
    const f4* xr = (const f4*)(xc + (size_t)i * DD);
    const f4* dr = (const f4*)(drift + (size_t)i * DD);
    const f4* nr = (const f4*)(noise + (size_t)i * DD);
    f4* ho = (f4*)(hpre + (size_t)i * DD);
    float h[DD];
#pragma unroll
    for (int q = 0; q < 4; q++) {
        f4 a = xr[q], b = dr[q], n = nr[q], o;
        o.x = a.x + step * (b.x - a.x) + n.x * 0.01f;
        o.y = a.y + step * (b.y - a.y) + n.y * 0.01f;
        o.z = a.z + step * (b.z - a.z) + n.z * 0.01f;
        o.w = a.w + step * (b.w - a.w) + n.w * 0.01f;
        ho[q] = o;
        h[4*q+0] = o.x; h[4*q+1] = o.y; h[4*q+2] = o.z; h[4*q+3] = o.w;
    }
    colstat_reduce_store(h, part, blockIdx.x, threadIdx.x);
}

__global__ __launch_bounds__(64) void k_stats_fin2(const double* __restrict__ part,
                                                   const float* __restrict__ stdx,
                                                   float* __restrict__ ratio) {
    const int c = threadIdx.x;
    if (c < DD) {
        double s = 0.0, q = 0.0;
        for (int b = 0; b < 32; b++) {
            s += part[(size_t)b * 2 * DD + c];
            q += part[(size_t)b * 2 * DD + DD + c];
        }
        double var = (q - s * s / (double)NN) / (double)(NN - 1);
        float stdh = (float)sqrt(var > 0.0 ? var : 0.0);
        ratio[c] = stdx[c] / (stdh + EPSF);
    }
}

// ---------------- final: out = h * ratio + mean (in place) ----------------
__global__ __launch_bounds__(256) void k_final(float* __restrict__ h,
                                               const float* __restrict__ ratio,
                                               const float* __restrict__ meanp) {
    const int i = blockIdx.x * 256 + threadIdx.x;
    const f4* rr = (const f4*)ratio;
    const f4* mr = (const f4*)meanp;
    f4* hr = (f4*)(h + (size_t)i * DD);
#pragma unroll
    for (int q = 0; q < 4; q++) {
        f4 v = hr[q], rv = rr[q], mv = mr[q];
        v.x = v.x * rv.x + mv.x;
        v.y = v.y * rv.y + mv.y;
        v.z = v.z * rv.z + mv.z;
        v.w = v.w * rv.w + mv.w;
        hr[q] = v;
    }
}

extern "C" void kernel_launch(void* const* d_in, const int* in_sizes, int n_in,
                              void* d_out, int out_size, void* d_ws, size_t ws_size,
                              hipStream_t stream) {
    (void)in_sizes; (void)n_in; (void)out_size; (void)ws_size;
    const float* x = (const float*)d_in[0];
    const float* noise = (const float*)d_in[1];
    const float* alpha = (const float*)d_in[2];
    float* out = (float*)d_out;

    double* part1 = (double*)d_ws;                        // 1024 dbl
    double* part2 = part1 + 1024;                         // 1024 dbl
    float*    xc   = (float*)(part2 + 1024);              // N*16
    uint32_t* xch  = (uint32_t*)(xc + (size_t)NN * DD);   // N*8
    float*    sqh  = (float*)(xch + (size_t)NN * 8);      // N
    float*    den  = sqh + NN;                            // N
    float*    s1p  = den + NN;                            // N*8
    float*    s2p  = s1p + (size_t)NN * CH;               // N*8
    float*    thr  = s2p + (size_t)NN * CH;               // N*2
    unsigned* cnt  = (unsigned*)(thr + (size_t)NN * 2);   // N
    float*    cand = (float*)(cnt + NN);                  // N*CAP (10.5MB)
    float*    sml  = cand + (size_t)NN * CAP;             // N*15
    float*    nump = sml + (size_t)NN * 15;               // N*8*16
    float*    wsp  = nump + (size_t)NN * CH * 16;         // N*8
    float*    drf  = wsp + (size_t)NN * CH;               // N*16
    float*    meanp = drf + (size_t)NN * DD;              // 16
    float*    stdx  = meanp + DD;                         // 16
    float*    ratio = stdx + DD;                          // 16
    int*      kptr  = (int*)(ratio + DD);                 // 1

    k_stats_part_x<<<32, 256, 0, stream>>>(x, part1);
    k_stats_fin1<<<1, 64, 0, stream>>>(part1, meanp, stdx);
    k_center<<<32, 256, 0, stream>>>(x, meanp, xc, xch, sqh, cnt);
    k_thresh<<<128, 512, 0, stream>>>(xch, sqh, thr);
    k_pass1_lean<<<512, 512, 0, stream>>>(xch, sqh, thr, s1p, s2p, cnt, cand);
    k_merge_den<<<32, 256, 0, stream>>>(s1p, s2p, den);
    k_adaptk<<<1, 1024, 0, stream>>>(den, kptr);
    k_sel15<<<NN / 8, 512, 0, stream>>>(cnt, cand, xch, sqh, sml);
    k_drift_mfma<<<512, 512, 0, stream>>>(xch, sqh, sml, kptr, nump, wsp);
    k_merge_drift<<<NN * DD / 256, 256, 0, stream>>>(nump, wsp, drf);
    k_hpre_stats<<<32, 256, 0, stream>>>(xc, drf, noise, alpha, out, part2);
    k_stats_fin2<<<1, 64, 0, stream>>>(part2, stdx, ratio);
    k_final<<<32, 256, 0, stream>>>(out, ratio, meanp);
}

// Round 7
// 167.587 us; speedup vs baseline: 1.5430x; 1.5430x over previous
//
#include <hip/hip_runtime.h>
#include <hip/hip_fp16.h>
#include <cfloat>
#include <cmath>
#include <cstdint>

#define NN 8192
#define DD 16
#define EPSF 1e-8f
#define CH2 16          // j-chunks of 512
#define CAPC 24         // candidate slots per (row, chunk)

typedef float4 f4;
typedef _Float16 f16x4 __attribute__((ext_vector_type(4)));
typedef _Float16 f16x2 __attribute__((ext_vector_type(2)));
typedef float f32x4 __attribute__((ext_vector_type(4)));

__device__ __forceinline__ unsigned umn(unsigned a, unsigned b) { return a < b ? a : b; }
__device__ __forceinline__ unsigned umx(unsigned a, unsigned b) { return a < b ? b : a; }

__device__ __forceinline__ uint32_t pkrtz(float a, float b) {
    return __builtin_bit_cast(uint32_t, __builtin_amdgcn_cvt_pkrtz(a, b));
}

__device__ __forceinline__ float fsqrt(float x) {
#if defined(__has_builtin) && __has_builtin(__builtin_amdgcn_sqrtf)
    return __builtin_amdgcn_sqrtf(x);
#else
    return sqrtf(x);
#endif
}

__device__ __forceinline__ float fexp2(float x) {
#if defined(__has_builtin) && __has_builtin(__builtin_amdgcn_exp2f)
    return __builtin_amdgcn_exp2f(x);
#else
    return exp2f(x);
#endif
}

// exact wave-shared top-15 insert (fallback path only)
__device__ __forceinline__ void topk_insert(unsigned (&lst)[15], unsigned& T, unsigned u) {
    unsigned long long m = __ballot(u < T);
    while (m) {
        int ln = (int)(__ffsll(m) - 1);
        unsigned v = (unsigned)__builtin_amdgcn_readlane((int)u, ln);
#pragma unroll
        for (int c = 0; c < 15; c++) {
            unsigned lo = umn(lst[c], v);
            unsigned hi = umx(lst[c], v);
            lst[c] = lo;
            v = hi;
        }
        T = lst[14];
        m &= m - 1;
        m &= __ballot(u < T);
    }
}

// ---------------- column-stat partials ----------------
__device__ __forceinline__ void colstat_reduce_store(const float h[DD], double* __restrict__ part,
                                                     int blk, int tid) {
    const int lane = tid & 63, wid = tid >> 6;
    double s[DD], s2[DD];
#pragma unroll
    for (int c = 0; c < DD; c++) { double a = (double)h[c]; s[c] = a; s2[c] = a * a; }
#pragma unroll
    for (int c = 0; c < DD; c++) {
#pragma unroll
        for (int off = 1; off < 64; off <<= 1) {
            s[c] += __shfl_xor(s[c], off);
            s2[c] += __shfl_xor(s2[c], off);
        }
    }
    __shared__ double red[4][2 * DD];
    if (lane == 0) {
#pragma unroll
        for (int c = 0; c < DD; c++) { red[wid][c] = s[c]; red[wid][DD + c] = s2[c]; }
    }
    __syncthreads();
    if (tid < 2 * DD) {
        double t = red[0][tid] + red[1][tid] + red[2][tid] + red[3][tid];
        part[(size_t)blk * 2 * DD + tid] = t;
    }
}

__global__ __launch_bounds__(256) void k_stats_part_x(const float* __restrict__ x,
                                                      double* __restrict__ part) {
    const int i = blockIdx.x * 256 + threadIdx.x;
    float h[DD];
    const f4* xr = (const f4*)(x + (size_t)i * DD);
#pragma unroll
    for (int q = 0; q < 4; q++) {
        f4 v = xr[q];
        h[4*q+0] = v.x; h[4*q+1] = v.y; h[4*q+2] = v.z; h[4*q+3] = v.w;
    }
    colstat_reduce_store(h, part, blockIdx.x, threadIdx.x);
}

__global__ __launch_bounds__(64) void k_stats_fin1(const double* __restrict__ part,
                                                   float* __restrict__ mean,
                                                   float* __restrict__ stdx) {
    const int c = threadIdx.x;
    if (c < DD) {
        double s = 0.0, q = 0.0;
        for (int b = 0; b < 32; b++) {
            s += part[(size_t)b * 2 * DD + c];
            q += part[(size_t)b * 2 * DD + DD + c];
        }
        double mu = s / (double)NN;
        double var = (q - s * s / (double)NN) / (double)(NN - 1);
        mean[c] = (float)mu;
        stdx[c] = (float)sqrt(var > 0.0 ? var : 0.0);
    }
}

// ---------------- center: xc=x-mean (f32), packed fp16 rows, sq of ROUNDED pts ----------------
__global__ __launch_bounds__(256) void k_center(const float* __restrict__ x,
                                                const float* __restrict__ meanp,
                                                float* __restrict__ xc,
                                                uint32_t* __restrict__ xch,
                                                float* __restrict__ sqh) {
    const int i = blockIdx.x * 256 + threadIdx.x;
    const f4* mr = (const f4*)meanp;
    const f4* xr = (const f4*)(x + (size_t)i * DD);
    f4* xo = (f4*)(xc + (size_t)i * DD);
    uint32_t* xh = xch + (size_t)i * 8;
    float s = 0.f;
#pragma unroll
    for (int q = 0; q < 4; q++) {
        f4 m = mr[q];
        f4 v = xr[q];
        v.x -= m.x; v.y -= m.y; v.z -= m.z; v.w -= m.w;
        xo[q] = v;
        _Float16 h0 = (_Float16)v.x, h1 = (_Float16)v.y, h2 = (_Float16)v.z, h3 = (_Float16)v.w;
        float r0 = (float)h0, r1 = (float)h1, r2 = (float)h2, r3 = (float)h3;
        s += r0 * r0 + r1 * r1 + r2 * r2 + r3 * r3;
        f16x2 p0 = {h0, h1}, p1 = {h2, h3};
        xh[q * 2 + 0] = __builtin_bit_cast(uint32_t, p0);
        xh[q * 2 + 1] = __builtin_bit_cast(uint32_t, p1);
    }
    sqh[i] = s;
}

// ---------------- thresh: per (row, 512-col half) sorted top-15 d2 list ----------------
// 256 threads = 4 waves = 4 i-tiles of 16 rows; j in [hc*512, hc*512+512)
__global__ __launch_bounds__(256, 2) void k_thresh(const uint32_t* __restrict__ xch,
                                                   const float* __restrict__ sqh,
                                                   float* __restrict__ smlh) {
    __shared__ uint32_t tileA[8 * 512];   // frag-order, 16KB
    __shared__ float sqs[512];            // 2KB
    __shared__ float lists[4][64][15];    // 15KB
    const int tid = threadIdx.x, wid = tid >> 6, lane = tid & 63;
    const int r = lane & 15, h = lane >> 4;
    const int iG = blockIdx.x >> 1, hc = blockIdx.x & 1;
    const int jbase = hc << 9;
    const int i0 = (iG * 4 + wid) << 4;
    const int i = i0 + r;

    uint2 bu = *(const uint2*)(xch + (size_t)i * 8 + h * 2);
    f16x4 bf = __builtin_bit_cast(f16x4, bu);
    const float sqi = sqh[i];

#pragma unroll
    for (int s = 0; s < 2; s++) {
        int jl = tid + s * 256;
        const uint4* src = (const uint4*)(xch + (size_t)(jbase + jl) * 8);
        uint4 a = src[0], b = src[1];
        uint32_t* base = tileA + ((jl >> 4) * 128 + (jl & 15) * 2);
        *(uint2*)(base)      = make_uint2(a.x, a.y);
        *(uint2*)(base + 32) = make_uint2(a.z, a.w);
        *(uint2*)(base + 64) = make_uint2(b.x, b.y);
        *(uint2*)(base + 96) = make_uint2(b.z, b.w);
        sqs[jl] = sqh[jbase + jl];
    }
    __syncthreads();

    unsigned lst[15];
#pragma unroll
    for (int c = 0; c < 15; c++) lst[c] = 0x7F7FFFFFu;
    unsigned T = 0x7F7FFFFFu, Tg = 0x7F7FFFFFu;

    for (int jt = 0; jt < 32; jt++) {
        uint2 au = *(const uint2*)(tileA + (jt * 128 + lane * 2));
        f16x4 af = __builtin_bit_cast(f16x4, au);
        f32x4 dot = __builtin_amdgcn_mfma_f32_16x16x16f16(af, bf, (f32x4){0.f, 0.f, 0.f, 0.f}, 0, 0, 0);
        f32x4 sq4 = *(const f32x4*)&sqs[jt * 16 + h * 4];
        bool fired = false;
#pragma unroll
        for (int q = 0; q < 4; q++) {
            float d2 = fmaf(-2.0f, dot[q], sqi + sq4[q]);
            float d2c = fmaxf(d2, 0.0f);
            unsigned u = __float_as_uint(d2c);
            if (u < Tg) {
                fired = true;
#pragma unroll
                for (int c = 0; c < 15; c++) {
                    unsigned lo = umn(lst[c], u), hi = umx(lst[c], u);
                    lst[c] = lo; u = hi;
                }
                T = lst[14];
            }
        }
        if (__any(fired)) {
            unsigned t1 = umn(T, (unsigned)__shfl_xor((int)T, 16));
            Tg = umn(t1, (unsigned)__shfl_xor((int)t1, 32));
        }
    }
    // merge 4 per-lane sorted lists -> row's sorted 15 over this half
#pragma unroll
    for (int c = 0; c < 15; c++) lists[wid][lane][c] = __uint_as_float(lst[c]);
    __syncthreads();
    if (h == 0) {
        int p0 = 0, p1 = 0, p2 = 0, p3 = 0;
        float* dst = smlh + ((size_t)i * 2 + hc) * 15;
        for (int rr = 0; rr < 15; rr++) {
            float v0 = (p0 < 15) ? lists[wid][r +  0][p0] : FLT_MAX;
            float v1 = (p1 < 15) ? lists[wid][r + 16][p1] : FLT_MAX;
            float v2 = (p2 < 15) ? lists[wid][r + 32][p2] : FLT_MAX;
            float v3 = (p3 < 15) ? lists[wid][r + 48][p3] : FLT_MAX;
            float m = fminf(fminf(v0, v1), fminf(v2, v3));
            if (v0 == m) p0++; else if (v1 == m) p1++; else if (v2 == m) p2++; else p3++;
            dst[rr] = m;
        }
    }
}

// ---------------- thr[i] = 15th smallest of the union of the two sorted half-lists ----------------
__global__ __launch_bounds__(256) void k_thrmerge(const float* __restrict__ smlh,
                                                  float* __restrict__ thr) {
    const int i = blockIdx.x * 256 + threadIdx.x;
    const float* A = smlh + (size_t)i * 30;
    const float* B = A + 15;
    int p0 = 0, p1 = 0;
    float m = 0.f;
    for (int rr = 0; rr < 15; rr++) {
        float va = A[p0], vb = B[p1];
        if (va <= vb) { m = va; p0++; } else { m = vb; p1++; }
    }
    thr[i] = m;  // >= true row 15th; candidates <= thr bounded (~120/row expected)
}

// ---------------- pass1 lean: s1/s2 partials + LDS-buffered candidate dump ----------------
__global__ __launch_bounds__(512, 8) void k_pass1_lean(const uint32_t* __restrict__ xch,
                                                       const float* __restrict__ sqh,
                                                       const float* __restrict__ thr,
                                                       float* __restrict__ s1p,
                                                       float* __restrict__ s2p,
                                                       unsigned* __restrict__ cntc,
                                                       float* __restrict__ cand) {
    __shared__ uint32_t tileA[8 * 512];       // 16KB frag-order
    __shared__ float sqs[512];                // 2KB
    __shared__ float clist[128][CAPC];        // 12KB candidate lists
    __shared__ unsigned ccnt[128];            // 512B
    const int tid = threadIdx.x, wid = tid >> 6, lane = tid & 63;
    const int r = lane & 15, h = lane >> 4;
    const int iG = blockIdx.x >> 4, chunk = blockIdx.x & 15;
    const int jbase = chunk << 9;
    const int i0 = (iG * 8 + wid) << 4;
    const int i = i0 + r;
    const int lrow = wid * 16 + r;

    uint2 bu = *(const uint2*)(xch + (size_t)i * 8 + h * 2);
    f16x4 bf = __builtin_bit_cast(f16x4, bu);
    const float sqi = sqh[i];
    const float Tf = thr[i];

    if (tid < 128) ccnt[tid] = 0;
    {
        int jl = tid;
        const uint4* src = (const uint4*)(xch + (size_t)(jbase + jl) * 8);
        uint4 a = src[0], b = src[1];
        uint32_t* base = tileA + ((jl >> 4) * 128 + (jl & 15) * 2);
        *(uint2*)(base)      = make_uint2(a.x, a.y);
        *(uint2*)(base + 32) = make_uint2(a.z, a.w);
        *(uint2*)(base + 64) = make_uint2(b.x, b.y);
        *(uint2*)(base + 96) = make_uint2(b.z, b.w);
        sqs[jl] = sqh[jbase + jl];
    }
    __syncthreads();

    float s1 = 0.f, s2 = 0.f;
    for (int jt = 0; jt < 32; jt++) {
        uint2 au = *(const uint2*)(tileA + (jt * 128 + lane * 2));
        f16x4 af = __builtin_bit_cast(f16x4, au);
        f32x4 dot = __builtin_amdgcn_mfma_f32_16x16x16f16(af, bf, (f32x4){0.f, 0.f, 0.f, 0.f}, 0, 0, 0);
        f32x4 sq4 = *(const f32x4*)&sqs[jt * 16 + h * 4];
#pragma unroll
        for (int q = 0; q < 4; q++) {
            float d2 = fmaf(-2.0f, dot[q], sqi + sq4[q]);
            float d2c = fmaxf(d2, 0.0f);
            s1 += fsqrt(d2c);
            s2 += d2c;
            if (d2c <= Tf) {                       // rare; LDS atomic, no HBM traffic
                unsigned idx = atomicAdd(&ccnt[lrow], 1u);
                if (idx < CAPC) clist[lrow][idx] = d2c;
            }
        }
    }
    s1 += __shfl_xor(s1, 16); s1 += __shfl_xor(s1, 32);
    s2 += __shfl_xor(s2, 16); s2 += __shfl_xor(s2, 32);
    if (h == 0) {
        s1p[(size_t)i * CH2 + chunk] = s1;
        s2p[(size_t)i * CH2 + chunk] = s2;
    }
    __syncthreads();
    if (tid < 128) {
        const int gi = iG * 128 + tid;
        const unsigned c = ccnt[tid];
        cntc[(size_t)chunk * NN + gi] = c;         // raw count (overflow detectable)
        const unsigned w = umn(c, (unsigned)CAPC);
        float* dst = cand + ((size_t)chunk * NN + gi) * CAPC;
        for (unsigned s = 0; s < w; s += 4)
            *(float4*)&dst[s] = *(const float4*)&clist[tid][s];
    }
}

// ---------------- sel15: exact top-15 per row from candidates (fallback: full rescan) ----------------
__global__ __launch_bounds__(512) void k_sel15(const unsigned* __restrict__ cntc,
                                               const float* __restrict__ cand,
                                               const uint32_t* __restrict__ xch,
                                               const float* __restrict__ sqh,
                                               float* __restrict__ sml) {
    const int tid = threadIdx.x, wid = tid >> 6, lane = tid & 63;
    const int i = blockIdx.x * 8 + wid;
    float v[CH2];
    bool over = false;
#pragma unroll
    for (int c = 0; c < CH2; c++) {
        unsigned n = cntc[(size_t)c * NN + i];
        over |= (n > (unsigned)CAPC);
        unsigned nn = umn(n, (unsigned)CAPC);
        v[c] = (lane < (int)nn) ? cand[((size_t)c * NN + i) * CAPC + lane] : FLT_MAX;
    }
    if (!__any(over)) {
        for (int rr = 0; rr < 15; rr++) {
            float m = v[0];
#pragma unroll
            for (int c = 1; c < CH2; c++) m = fminf(m, v[c]);
            float wm = m;
#pragma unroll
            for (int off = 1; off < 64; off <<= 1) wm = fminf(wm, __shfl_xor(wm, off));
            unsigned long long b = __ballot(m == wm);
            if (lane == (int)(__ffsll(b) - 1)) {   // consume exactly one slot
                bool done = false;
#pragma unroll
                for (int c = 0; c < CH2; c++) {
                    bool hit = !done && (v[c] == wm);
                    v[c] = hit ? FLT_MAX : v[c];
                    done = done || hit;
                }
            }
            if (lane == 0) sml[(size_t)i * 15 + rr] = wm;
        }
    } else {
        // exact full-row rescan (expected O(1) rows per launch)
        uint32_t xi[8];
        {
            const uint4* p = (const uint4*)(xch + (size_t)i * 8);
            uint4 a = p[0], b = p[1];
            xi[0] = a.x; xi[1] = a.y; xi[2] = a.z; xi[3] = a.w;
            xi[4] = b.x; xi[5] = b.y; xi[6] = b.z; xi[7] = b.w;
        }
        const float sqi = sqh[i];
        unsigned lst[15];
#pragma unroll
        for (int c = 0; c < 15; c++) lst[c] = 0x7F7FFFFFu;
        unsigned T = 0x7F7FFFFFu;
        for (int jb = 0; jb < NN; jb += 64) {
            int j = jb + lane;
            const uint4* p = (const uint4*)(xch + (size_t)j * 8);
            uint4 a = p[0], b = p[1];
            uint32_t xj[8] = {a.x, a.y, a.z, a.w, b.x, b.y, b.z, b.w};
            float dot = 0.f;
#pragma unroll
            for (int c = 0; c < 8; c++)
                dot = __builtin_amdgcn_fdot2(__builtin_bit_cast(f16x2, xi[c]),
                                             __builtin_bit_cast(f16x2, xj[c]), dot, false);
            float d2c = fmaxf(fmaf(-2.0f, dot, sqi + sqh[j]), 0.0f);
            topk_insert(lst, T, __float_as_uint(d2c));
        }
        if (lane == 0) {
#pragma unroll
            for (int c = 0; c < 15; c++) sml[(size_t)i * 15 + c] = __uint_as_float(lst[c]);
        }
    }
}

// ---------------- density from s1/s2 partials ----------------
__global__ __launch_bounds__(256) void k_merge_den(const float* __restrict__ s1p,
                                                   const float* __restrict__ s2p,
                                                   float* __restrict__ den) {
    const int i = blockIdx.x * 256 + threadIdx.x;
    double g1 = 0.0, g2 = 0.0;
#pragma unroll
    for (int c = 0; c < CH2; c++) {
        g1 += (double)s1p[(size_t)i * CH2 + c];
        g2 += (double)s2p[(size_t)i * CH2 + c];
    }
    double var = (g2 - g1 * g1 / (double)NN) / (double)(NN - 1);
    den[i] = (float)sqrt(var > 0.0 ? var : 0.0);
}

// ---------------- global adaptive k ----------------
__global__ __launch_bounds__(1024) void k_adaptk(const float* __restrict__ density,
                                                 int* __restrict__ kout) {
    const int tid = threadIdx.x;
    __shared__ float redf[16];
    __shared__ int redi[16];
    __shared__ float dmax_sh;
    const int wid = tid >> 6, lane = tid & 63;
    float mx = 0.f;
    for (int r = tid; r < NN; r += 1024) mx = fmaxf(mx, density[r]);
#pragma unroll
    for (int off = 1; off < 64; off <<= 1) mx = fmaxf(mx, __shfl_xor(mx, off));
    if (lane == 0) redf[wid] = mx;
    __syncthreads();
    if (tid == 0) {
        float m = redf[0];
        for (int w = 1; w < 16; w++) m = fmaxf(m, redf[w]);
        dmax_sh = m;
    }
    __syncthreads();
    const float dmax = dmax_sh + EPSF;
    int ks = 0;
    for (int r = tid; r < NN; r += 1024) {
        float f = density[r] / dmax;
        float kf = fminf(fmaxf(5.0f + 10.0f * f, 5.0f), 20.0f);
        ks += (int)kf;
    }
#pragma unroll
    for (int off = 1; off < 64; off <<= 1) ks += __shfl_xor(ks, off);
    if (lane == 0) redi[wid] = ks;
    __syncthreads();
    if (tid == 0) {
        int t = 0;
        for (int w = 0; w < 16; w++) t += redi[w];
        float meank = (float)t / (float)NN;
        kout[0] = (int)meank;
    }
}

// ---------------- drift (MFMA QK + MFMA PV): partial numerator/wsum per chunk ----------------
__global__ __launch_bounds__(512, 8) void k_drift_mfma(const uint32_t* __restrict__ xch,
                                                       const float* __restrict__ sqh,
                                                       const float* __restrict__ sml,
                                                       const int* __restrict__ kptr,
                                                       float* __restrict__ nump,
                                                       float* __restrict__ wsp) {
    __shared__ uint32_t tileA[8 * 512];    // frag-order, 16KB
    __shared__ uint32_t tileT[16 * 256];   // transposed [d][jpair] +2d rotated, 16KB
    __shared__ float sqs[512];             // 2KB
    const int tid = threadIdx.x, wid = tid >> 6, lane = tid & 63;
    const int r = lane & 15, h = lane >> 4;
    const int iG = blockIdx.x >> 4, chunk = blockIdx.x & 15;
    const int jb = chunk << 9;
    const int i0 = (iG * 8 + wid) << 4;
    const int i = i0 + r;

    const int k = kptr[0];
    const float sig2 = sml[(size_t)i * 15 + (k - 1)];   // k-th smallest d2 == sigma^2
    const float nl2 = -1.4426950408889634f / (2.0f * sig2 + EPSF);  // fold log2e into exp2
    uint2 bu = *(const uint2*)(xch + (size_t)i * 8 + h * 2);
    f16x4 bf = __builtin_bit_cast(f16x4, bu);
    const float sqi = sqh[i];

    f32x4 acc = {0.f, 0.f, 0.f, 0.f};
    float ws = 0.f;

    {
        int jl = tid;
        const uint4* src = (const uint4*)(xch + (size_t)(jb + jl) * 8);
        uint4 a = src[0], b = src[1];
        uint32_t* base = tileA + ((jl >> 4) * 128 + (jl & 15) * 2);
        *(uint2*)(base)      = make_uint2(a.x, a.y);
        *(uint2*)(base + 32) = make_uint2(a.z, a.w);
        *(uint2*)(base + 64) = make_uint2(b.x, b.y);
        *(uint2*)(base + 96) = make_uint2(b.z, b.w);
        sqs[jl] = sqh[jb + jl];
        if (tid < 256) {
            int jp = tid;
            const uint4* sA = (const uint4*)(xch + (size_t)(jb + 2 * jp) * 8);
            const uint4* sB = (const uint4*)(xch + (size_t)(jb + 2 * jp + 1) * 8);
            uint4 a0 = sA[0], a1 = sA[1], b0 = sB[0], b1 = sB[1];
            uint32_t rA[8] = {a0.x, a0.y, a0.z, a0.w, a1.x, a1.y, a1.z, a1.w};
            uint32_t rB[8] = {b0.x, b0.y, b0.z, b0.w, b1.x, b1.y, b1.z, b1.w};
#pragma unroll
            for (int d = 0; d < 16; d++) {
                uint32_t lo = (d & 1) ? (rA[d >> 1] >> 16) : (rA[d >> 1] & 0xFFFFu);
                uint32_t hi = (d & 1) ? (rB[d >> 1] & 0xFFFF0000u) : (rB[d >> 1] << 16);
                tileT[d * 256 + ((jp + 2 * d) & 255)] = lo | hi;
            }
        }
    }
    __syncthreads();
    for (int jt = 0; jt < 32; jt++) {
        uint2 au = *(const uint2*)(tileA + (jt * 128 + lane * 2));
        f16x4 af = __builtin_bit_cast(f16x4, au);
        f32x4 dot = __builtin_amdgcn_mfma_f32_16x16x16f16(af, bf, (f32x4){0.f, 0.f, 0.f, 0.f}, 0, 0, 0);
        f32x4 sq4 = *(const f32x4*)&sqs[jt * 16 + h * 4];
        float w0, w1, w2, w3;
        {
            float d2, d;
            d2 = fmaf(-2.f, dot[0], sqi + sq4[0]); d = fsqrt(fmaxf(d2, 0.f)); w0 = fexp2(d * nl2);
            d2 = fmaf(-2.f, dot[1], sqi + sq4[1]); d = fsqrt(fmaxf(d2, 0.f)); w1 = fexp2(d * nl2);
            d2 = fmaf(-2.f, dot[2], sqi + sq4[2]); d = fsqrt(fmaxf(d2, 0.f)); w2 = fexp2(d * nl2);
            d2 = fmaf(-2.f, dot[3], sqi + sq4[3]); d = fsqrt(fmaxf(d2, 0.f)); w3 = fexp2(d * nl2);
        }
        ws += (w0 + w1) + (w2 + w3);
        uint2 wp = make_uint2(pkrtz(w0, w1), pkrtz(w2, w3));
        f16x4 wf = __builtin_bit_cast(f16x4, wp);
        int jp0 = jt * 8 + h * 2;
        uint2 tv = *(const uint2*)(tileT + (r * 256 + ((jp0 + 2 * r) & 255)));
        f16x4 btf = __builtin_bit_cast(f16x4, tv);
        acc = __builtin_amdgcn_mfma_f32_16x16x16f16(wf, btf, acc, 0, 0, 0);
    }
    ws += __shfl_xor(ws, 16); ws += __shfl_xor(ws, 32);
    if (h == 0) wsp[(size_t)i * CH2 + chunk] = ws;
#pragma unroll
    for (int q = 0; q < 4; q++) {
        int irow = i0 + h * 4 + q;
        nump[((size_t)irow * CH2 + chunk) * 16 + r] = acc[q];
    }
}

// ---------------- merge drift partials ----------------
__global__ __launch_bounds__(256) void k_merge_drift(const float* __restrict__ nump,
                                                     const float* __restrict__ wsp,
                                                     float* __restrict__ drf) {
    const int t = blockIdx.x * 256 + threadIdx.x;
    const int i = t >> 4, d = t & 15;
    float s = 0.f;
#pragma unroll
    for (int c = 0; c < CH2; c++) s += nump[((size_t)i * CH2 + c) * 16 + d];
    float w = 0.f;
#pragma unroll
    for (int c = 0; c < CH2; c++) w += wsp[(size_t)i * CH2 + c];
    drf[t] = s / (w + EPSF);
}

// ---------------- fused: h = xc + step*(drift-xc) + 0.01*noise; col-stat partials ----------------
__global__ __launch_bounds__(256) void k_hpre_stats(const float* __restrict__ xc,
                                                    const float* __restrict__ drift,
                                                    const float* __restrict__ noise,
                                                    const float* __restrict__ alpha,
                                                    float* __restrict__ hpre,
                                                    double* __restrict__ part) {
    const int i = blockIdx.x * 256 + threadIdx.x;
    const float step = powf(16.0f, -alpha[0]);
    const f4* xr = (const f4*)(xc + (size_t)i * DD);
    const f4* dr = (const f4*)(drift + (size_t)i * DD);
    const f4* nr = (const f4*)(noise + (size_t)i * DD);
    f4* ho = (f4*)(hpre + (size_t)i * DD);
    float h[DD];
#pragma unroll
    for (int q = 0; q < 4; q++) {
        f4 a = xr[q], b = dr[q], n = nr[q], o;
        o.x = a.x + step * (b.x - a.x) + n.x * 0.01f;
        o.y = a.y + step * (b.y - a.y) + n.y * 0.01f;
        o.z = a.z + step * (b.z - a.z) + n.z * 0.01f;
        o.w = a.w + step * (b.w - a.w) + n.w * 0.01f;
        ho[q] = o;
        h[4*q+0] = o.x; h[4*q+1] = o.y; h[4*q+2] = o.z; h[4*q+3] = o.w;
    }
    colstat_reduce_store(h, part, blockIdx.x, threadIdx.x);
}

__global__ __launch_bounds__(64) void k_stats_fin2(const double* __restrict__ part,
                                                   const float* __restrict__ stdx,
                                                   float* __restrict__ ratio) {
    const int c = threadIdx.x;
    if (c < DD) {
        double s = 0.0, q = 0.0;
        for (int b = 0; b < 32; b++) {
            s += part[(size_t)b * 2 * DD + c];
            q += part[(size_t)b * 2 * DD + DD + c];
        }
        double var = (q - s * s / (double)NN) / (double)(NN - 1);
        float stdh = (float)sqrt(var > 0.0 ? var : 0.0);
        ratio[c] = stdx[c] / (stdh + EPSF);
    }
}

// ---------------- final: out = h * ratio + mean (in place) ----------------
__global__ __launch_bounds__(256) void k_final(float* __restrict__ h,
                                               const float* __restrict__ ratio,
                                               const float* __restrict__ meanp) {
    const int i = blockIdx.x * 256 + threadIdx.x;
    const f4* rr = (const f4*)ratio;
    const f4* mr = (const f4*)meanp;
    f4* hr = (f4*)(h + (size_t)i * DD);
#pragma unroll
    for (int q = 0; q < 4; q++) {
        f4 v = hr[q], rv = rr[q], mv = mr[q];
        v.x = v.x * rv.x + mv.x;
        v.y = v.y * rv.y + mv.y;
        v.z = v.z * rv.z + mv.z;
        v.w = v.w * rv.w + mv.w;
        hr[q] = v;
    }
}

extern "C" void kernel_launch(void* const* d_in, const int* in_sizes, int n_in,
                              void* d_out, int out_size, void* d_ws, size_t ws_size,
                              hipStream_t stream) {
    (void)in_sizes; (void)n_in; (void)out_size; (void)ws_size;
    const float* x = (const float*)d_in[0];
    const float* noise = (const float*)d_in[1];
    const float* alpha = (const float*)d_in[2];
    float* out = (float*)d_out;

    double* part1 = (double*)d_ws;                        // 1024 dbl
    double* part2 = part1 + 1024;                         // 1024 dbl
    float*    xc   = (float*)(part2 + 1024);              // N*16
    uint32_t* xch  = (uint32_t*)(xc + (size_t)NN * DD);   // N*8
    float*    sqh  = (float*)(xch + (size_t)NN * 8);      // N
    float*    den  = sqh + NN;                            // N
    float*    smlh = den + NN;                            // N*2*15
    float*    thr  = smlh + (size_t)NN * 30;              // N
    float*    s1p  = thr + NN;                            // N*16
    float*    s2p  = s1p + (size_t)NN * CH2;              // N*16
    unsigned* cntc = (unsigned*)(s2p + (size_t)NN * CH2); // 16*N
    float*    cand = (float*)(cntc + (size_t)CH2 * NN);   // 16*N*24 (12.6MB)
    float*    sml  = cand + (size_t)CH2 * NN * CAPC;      // N*15
    float*    nump = sml + (size_t)NN * 15;               // N*16*16 (8MB)
    float*    wsp  = nump + (size_t)NN * CH2 * 16;        // N*16
    float*    drf  = wsp + (size_t)NN * CH2;              // N*16
    float*    meanp = drf + (size_t)NN * DD;              // 16
    float*    stdx  = meanp + DD;                         // 16
    float*    ratio = stdx + DD;                          // 16
    int*      kptr  = (int*)(ratio + DD);                 // 1

    k_stats_part_x<<<32, 256, 0, stream>>>(x, part1);
    k_stats_fin1<<<1, 64, 0, stream>>>(part1, meanp, stdx);
    k_center<<<32, 256, 0, stream>>>(x, meanp, xc, xch, sqh);
    k_thresh<<<256, 256, 0, stream>>>(xch, sqh, smlh);
    k_thrmerge<<<32, 256, 0, stream>>>(smlh, thr);
    k_pass1_lean<<<1024, 512, 0, stream>>>(xch, sqh, thr, s1p, s2p, cntc, cand);
    k_merge_den<<<32, 256, 0, stream>>>(s1p, s2p, den);
    k_adaptk<<<1, 1024, 0, stream>>>(den, kptr);
    k_sel15<<<1024, 512, 0, stream>>>(cntc, cand, xch, sqh, sml);
    k_drift_mfma<<<1024, 512, 0, stream>>>(xch, sqh, sml, kptr, nump, wsp);
    k_merge_drift<<<512, 256, 0, stream>>>(nump, wsp, drf);
    k_hpre_stats<<<32, 256, 0, stream>>>(xc, drf, noise, alpha, out, part2);
    k_stats_fin2<<<1, 64, 0, stream>>>(part2, stdx, ratio);
    k_final<<<32, 256, 0, stream>>>(out, ratio, meanp);
}